// Round 1
// baseline (1185.527 us; speedup 1.0000x reference)
//
#include <hip/hip_runtime.h>
#include <math.h>

#define T_TOK 4096
#define A_DIM 1024
#define E_DIM 512
#define N_SPAN 32768
#define W_MAX 10
#define HID 150
#define FD 20

// ---------------------------------------------------------------------------
// Kernel 1: per-token attention MLP -> attns[T]
// grid: T/TPB blocks x 256 threads; each block handles TPB tokens so Wa1
// (614 KB) is re-read only T/TPB times from L2.
// ---------------------------------------------------------------------------
#define TPB 16

__global__ __launch_bounds__(256) void attn_mlp_kernel(
    const float* __restrict__ states, const float* __restrict__ Wa1,
    const float* __restrict__ ba1, const float* __restrict__ Wa2,
    const float* __restrict__ ba2, const float* __restrict__ Wa3,
    const float* __restrict__ ba3, float* __restrict__ attns)
{
    __shared__ float s_chunk[TPB][256];   // 16 KB staging of states rows
    __shared__ float s_h1[TPB][152];
    __shared__ float s_h2[TPB][152];

    const int tid = threadIdx.x;
    const int t0 = blockIdx.x * TPB;
    const int j = tid;

    float acc[TPB];
#pragma unroll
    for (int s = 0; s < TPB; ++s) acc[s] = 0.f;

    for (int kc = 0; kc < A_DIM; kc += 256) {
        __syncthreads();
#pragma unroll
        for (int i = 0; i < TPB; ++i)
            s_chunk[i][tid] = states[(size_t)(t0 + i) * A_DIM + kc + tid];
        __syncthreads();
        if (j < HID) {
            const float* wp = Wa1 + (size_t)kc * HID + j;
            for (int k = 0; k < 256; ++k) {
                float w = wp[(size_t)k * HID];
#pragma unroll
                for (int s = 0; s < TPB; ++s) acc[s] += s_chunk[s][k] * w;
            }
        }
    }
    if (j < HID) {
        float b = ba1[j];
#pragma unroll
        for (int s = 0; s < TPB; ++s) s_h1[s][j] = fmaxf(acc[s] + b, 0.f);
    }
    __syncthreads();
    if (j < HID) {
        float acc2[TPB];
#pragma unroll
        for (int s = 0; s < TPB; ++s) acc2[s] = 0.f;
        for (int k = 0; k < HID; ++k) {
            float w = Wa2[k * HID + j];
#pragma unroll
            for (int s = 0; s < TPB; ++s) acc2[s] += s_h1[s][k] * w;
        }
        float b = ba2[j];
#pragma unroll
        for (int s = 0; s < TPB; ++s) s_h2[s][j] = fmaxf(acc2[s] + b, 0.f);
    }
    __syncthreads();
    if (tid < TPB) {
        float sum = ba3[0];
        for (int k = 0; k < HID; ++k) sum += s_h2[tid][k] * Wa3[k];
        attns[t0 + tid] = sum;
    }
}

// ---------------------------------------------------------------------------
// Kernel 2: fused span kernel. Each block handles SPB spans:
//   softmax over <=10 positions, attn_sum[512] into LDS, width-bin feature,
//   then the 2580->150->150->1 MLP with register tiling (acc[SPB] per output
//   column j) so Ws1 (1.5 MB) is read once per SPB spans.
// ---------------------------------------------------------------------------
#define SPB 16

__global__ __launch_bounds__(256) void span_kernel(
    const float* __restrict__ states, const float* __restrict__ embeds,
    const int* __restrict__ span_starts, const int* __restrict__ span_widths,
    const float* __restrict__ attns, const float* __restrict__ width_emb,
    const float* __restrict__ Ws1, const float* __restrict__ bs1,
    const float* __restrict__ Ws2, const float* __restrict__ bs2,
    const float* __restrict__ Ws3, const float* __restrict__ bs3,
    float* __restrict__ out)
{
    __shared__ float s_asum[SPB][E_DIM];   // 32 KB; later aliased as h2
    __shared__ float s_stage[SPB][256];    // 16 KB staging; later aliased as h1
    __shared__ float s_wgt[SPB][W_MAX];
    __shared__ int   s_pos[SPB][W_MAX];
    __shared__ float s_size[SPB][FD];
    __shared__ int   s_start[SPB], s_end[SPB], s_bin[SPB];

    const int tid = threadIdx.x;
    const int n0 = blockIdx.x * SPB;

    // ---- phase 1: span metadata + logits ----
    if (tid < SPB) {
        int st = span_starts[n0 + tid];
        int wd = span_widths[n0 + tid];
        s_start[tid] = st;
        s_end[tid] = st + wd - 1;
    }
    if (tid < SPB * W_MAX) {
        int s = tid / W_MAX, w = tid % W_MAX;
        int st = span_starts[n0 + s], wd = span_widths[n0 + s];
        int p = st + w;
        if (p > T_TOK - 1) p = T_TOK - 1;
        s_pos[s][w] = p;
        s_wgt[s][w] = (w < wd) ? attns[p] : -1e30f;
    }
    __syncthreads();

    // ---- softmax (one thread per span; only 10 elements) + bin ----
    if (tid < SPB) {
        int s = tid;
        float m = -1e30f;
#pragma unroll
        for (int w = 0; w < W_MAX; ++w) m = fmaxf(m, s_wgt[s][w]);
        float e[W_MAX];
        float sum = 0.f;
#pragma unroll
        for (int w = 0; w < W_MAX; ++w) { e[w] = expf(s_wgt[s][w] - m); sum += e[w]; }
        float inv = 1.f / sum;
#pragma unroll
        for (int w = 0; w < W_MAX; ++w) s_wgt[s][w] = e[w] * inv;
        int wd = span_widths[n0 + s];
        s_bin[s] = (wd >= 1) + (wd >= 2) + (wd >= 3) + (wd >= 4) +
                   (wd >= 8) + (wd >= 16) + (wd >= 32) + (wd >= 64);
    }
    __syncthreads();

    // ---- phase 2: width feature + attn_sum into LDS ----
    for (int idx = tid; idx < SPB * FD; idx += 256) {
        int s = idx / FD, f = idx % FD;
        s_size[s][f] = width_emb[s_bin[s] * FD + f];
    }
    {
        const int e0 = tid, e1 = tid + 256;
#pragma unroll
        for (int s = 0; s < SPB; ++s) {
            float v0 = 0.f, v1 = 0.f;
            for (int w = 0; w < W_MAX; ++w) {
                float wgt = s_wgt[s][w];
                if (wgt != 0.f) {
                    const float* ep = embeds + (size_t)s_pos[s][w] * E_DIM;
                    v0 += wgt * ep[e0];
                    v1 += wgt * ep[e1];
                }
            }
            s_asum[s][e0] = v0;
            s_asum[s][e1] = v1;
        }
    }
    __syncthreads();

    // ---- phase 3: g @ Ws1 (2580 x 150), register-tiled over SPB spans ----
    const int j = tid;
    float acc[SPB];
#pragma unroll
    for (int s = 0; s < SPB; ++s) acc[s] = 0.f;

    for (int seg = 0; seg < 2; ++seg) {
        for (int kc = 0; kc < A_DIM; kc += 256) {
            __syncthreads();
#pragma unroll
            for (int i = 0; i < SPB; ++i) {
                int row = seg ? s_end[i] : s_start[i];
                s_stage[i][tid] = states[(size_t)row * A_DIM + kc + tid];
            }
            __syncthreads();
            if (j < HID) {
                const float* wp = Ws1 + (size_t)(seg * A_DIM + kc) * HID + j;
#pragma unroll 4
                for (int k = 0; k < 256; ++k) {
                    float w = wp[(size_t)k * HID];
#pragma unroll
                    for (int s = 0; s < SPB; ++s) acc[s] += s_stage[s][k] * w;
                }
            }
        }
    }
    __syncthreads();
    if (j < HID) {
        // segment C: attn_sum (k = 2048..2559)
        const float* wp = Ws1 + (size_t)(2 * A_DIM) * HID + j;
#pragma unroll 4
        for (int k = 0; k < E_DIM; ++k) {
            float w = wp[(size_t)k * HID];
#pragma unroll
            for (int s = 0; s < SPB; ++s) acc[s] += s_asum[s][k] * w;
        }
        // segment D: width feature (k = 2560..2579)
        const float* wp2 = Ws1 + (size_t)(2 * A_DIM + E_DIM) * HID + j;
#pragma unroll
        for (int k = 0; k < FD; ++k) {
            float w = wp2[(size_t)k * HID];
#pragma unroll
            for (int s = 0; s < SPB; ++s) acc[s] += s_size[s][k] * w;
        }
    }
    __syncthreads();

    // ---- h1 = relu(acc + bs1) -> alias s_stage ----
    float (*s_h1)[152] = (float(*)[152]) & s_stage[0][0];
    if (j < HID) {
        float b = bs1[j];
#pragma unroll
        for (int s = 0; s < SPB; ++s) s_h1[s][j] = fmaxf(acc[s] + b, 0.f);
    }
    __syncthreads();

    // ---- h2 = relu(h1 @ Ws2 + bs2) -> alias s_asum ----
    float (*s_h2)[152] = (float(*)[152]) & s_asum[0][0];
    if (j < HID) {
        float acc2[SPB];
#pragma unroll
        for (int s = 0; s < SPB; ++s) acc2[s] = 0.f;
        for (int k = 0; k < HID; ++k) {
            float w = Ws2[k * HID + j];
#pragma unroll
            for (int s = 0; s < SPB; ++s) acc2[s] += s_h1[s][k] * w;
        }
        float b = bs2[j];
#pragma unroll
        for (int s = 0; s < SPB; ++s) s_h2[s][j] = fmaxf(acc2[s] + b, 0.f);
    }
    __syncthreads();

    // ---- score = h2 @ Ws3 + bs3 ----
    if (tid < SPB) {
        float sum = bs3[0];
        for (int k = 0; k < HID; ++k) sum += s_h2[tid][k] * Ws3[k];
        out[n0 + tid] = sum;
    }
}

// ---------------------------------------------------------------------------
extern "C" void kernel_launch(void* const* d_in, const int* in_sizes, int n_in,
                              void* d_out, int out_size, void* d_ws, size_t ws_size,
                              hipStream_t stream)
{
    const float* states      = (const float*)d_in[0];
    const float* embeds      = (const float*)d_in[1];
    const int*   span_starts = (const int*)d_in[2];
    const int*   span_widths = (const int*)d_in[3];
    const float* Wa1 = (const float*)d_in[4];
    const float* ba1 = (const float*)d_in[5];
    const float* Wa2 = (const float*)d_in[6];
    const float* ba2 = (const float*)d_in[7];
    const float* Wa3 = (const float*)d_in[8];
    const float* ba3 = (const float*)d_in[9];
    const float* width_emb = (const float*)d_in[10];
    const float* Ws1 = (const float*)d_in[11];
    const float* bs1 = (const float*)d_in[12];
    const float* Ws2 = (const float*)d_in[13];
    const float* bs2 = (const float*)d_in[14];
    const float* Ws3 = (const float*)d_in[15];
    const float* bs3 = (const float*)d_in[16];
    float* out   = (float*)d_out;
    float* attns = (float*)d_ws;   // 4096 floats of scratch; fully rewritten each call

    hipLaunchKernelGGL(attn_mlp_kernel, dim3(T_TOK / TPB), dim3(256), 0, stream,
                       states, Wa1, ba1, Wa2, ba2, Wa3, ba3, attns);
    hipLaunchKernelGGL(span_kernel, dim3(N_SPAN / SPB), dim3(256), 0, stream,
                       states, embeds, span_starts, span_widths, attns, width_emb,
                       Ws1, bs1, Ws2, bs2, Ws3, bs3, out);
}

// Round 2
// 284.825 us; speedup vs baseline: 4.1623x; 4.1623x over previous
//
#include <hip/hip_runtime.h>
#include <math.h>

#define T_TOK 4096
#define A_DIM 1024
#define E_DIM 512
#define N_SPAN 32768
#define W_MAX 10
#define HID 150
#define FD 20

#define PCOL 152          // padded column count for token projections
#define HSTR 68           // LDS row stride (floats) for 64-wide tiles

// ws layout (floats): attns[4096] @0, WE1[9*152] @4096, P[4][4096][152] @6144
#define WS_ATTNS 0
#define WS_WE1   4096
#define WS_P     6144

__device__ __forceinline__ float4 ld4(const float* p) { return *(const float4*)p; }

// ---------------------------------------------------------------------------
// Token projection GEMM: P_g[4096][152] = X_g @ W_g  (64x64 tiles, 4x4 micro)
//   g=0: states @ Wa1          (K=1024)  -> attn-MLP layer-1 pre-act
//   g=1: states @ Ws1[0:1024]  (K=1024)  -> start-token projection
//   g=2: states @ Ws1[1024:2048]         -> end-token projection
//   g=3: embeds @ Ws1[2048:2560] (K=512) -> embed projection
// cols 150,151 written as 0; no bias added here.
// ---------------------------------------------------------------------------
__global__ __launch_bounds__(256) void token_gemm_kernel(
    const float* __restrict__ states, const float* __restrict__ embeds,
    const float* __restrict__ Wa1, const float* __restrict__ Ws1,
    float* __restrict__ P)
{
    __shared__ float sA[16][HSTR];   // k-major A tile (transposed)
    __shared__ float sB[16][HSTR];

    const int tid = threadIdx.x;
    const int m0 = blockIdx.x * 64;
    const int n0 = blockIdx.y * 64;
    const int g = blockIdx.z;

    const float* X; const float* W; int K, ldx;
    if (g == 0)      { X = states; W = Wa1;              K = 1024; ldx = 1024; }
    else if (g == 1) { X = states; W = Ws1;              K = 1024; ldx = 1024; }
    else if (g == 2) { X = states; W = Ws1 + 1024 * HID; K = 1024; ldx = 1024; }
    else             { X = embeds; W = Ws1 + 2048 * HID; K = 512;  ldx = 512;  }
    float* Pg = P + (size_t)g * T_TOK * PCOL;

    const int ar = tid >> 2, aq = tid & 3;   // A staging: row 0..63, quad 0..3
    const int bk = tid >> 4, bc = tid & 15;  // B staging: k 0..15, col-quad 0..15
    const int tm = tid >> 4, tn = tid & 15;  // compute mapping

    float acc[4][4];
#pragma unroll
    for (int i = 0; i < 4; ++i)
#pragma unroll
        for (int j = 0; j < 4; ++j) acc[i][j] = 0.f;

    const float* Arow = X + (size_t)(m0 + ar) * ldx + 4 * aq;

    for (int k0 = 0; k0 < K; k0 += 16) {
        __syncthreads();
        float4 av = ld4(Arow + k0);
        sA[4 * aq + 0][ar] = av.x;
        sA[4 * aq + 1][ar] = av.y;
        sA[4 * aq + 2][ar] = av.z;
        sA[4 * aq + 3][ar] = av.w;
        {
            const float* wrow = W + (size_t)(k0 + bk) * HID;
#pragma unroll
            for (int i = 0; i < 4; ++i) {
                int col = n0 + 4 * bc + i;
                sB[bk][4 * bc + i] = wrow[col < HID ? col : HID - 1];
            }
        }
        __syncthreads();
#pragma unroll
        for (int k = 0; k < 16; ++k) {
            float4 af = ld4(&sA[k][4 * tm]);
            float4 bf = ld4(&sB[k][4 * tn]);
            float a[4] = {af.x, af.y, af.z, af.w};
            float b[4] = {bf.x, bf.y, bf.z, bf.w};
#pragma unroll
            for (int i = 0; i < 4; ++i)
#pragma unroll
                for (int j = 0; j < 4; ++j)
                    acc[i][j] = fmaf(a[i], b[j], acc[i][j]);
        }
    }

#pragma unroll
    for (int i = 0; i < 4; ++i) {
        float* prow = Pg + (size_t)(m0 + 4 * tm + i) * PCOL;
#pragma unroll
        for (int j = 0; j < 4; ++j) {
            int col = n0 + 4 * tn + j;
            if (col < PCOL) prow[col] = (col < HID) ? acc[i][j] : 0.f;
        }
    }
}

// ---------------------------------------------------------------------------
// WE1[9][152] = width_emb @ Ws1[2560:2580]  (tiny)
// ---------------------------------------------------------------------------
__global__ void we1_kernel(const float* __restrict__ width_emb,
                           const float* __restrict__ Ws1,
                           float* __restrict__ WE1)
{
    int idx = blockIdx.x * 256 + threadIdx.x;
    if (idx >= 9 * PCOL) return;
    int b = idx / PCOL, j = idx % PCOL;
    float acc = 0.f;
    if (j < HID) {
        for (int k = 0; k < FD; ++k)
            acc = fmaf(width_emb[b * FD + k], Ws1[(size_t)(2560 + k) * HID + j], acc);
    }
    WE1[idx] = acc;
}

// ---------------------------------------------------------------------------
// Shared MLP tail: given h1 (biased+relu'd) in transposed LDS sH[k][row],
// compute relu(h1 @ W2 + b2) @ W3 + b3 for 64 rows -> out[row0..row0+63].
// ---------------------------------------------------------------------------
__device__ __forceinline__ void mlp_tail_150(
    float (&sH)[PCOL][HSTR], float (&sB)[16][HSTR],
    const float* __restrict__ W2, const float* __restrict__ b2,
    const float* __restrict__ W3, const float* __restrict__ b3,
    float* __restrict__ out, int row0)
{
    const int tid = threadIdx.x;
    const int tm = tid >> 4, tn = tid & 15;
    float sc[4] = {0.f, 0.f, 0.f, 0.f};

    for (int nc = 0; nc < 3; ++nc) {
        const int n0 = nc * 64;
        float acc[4][4];
#pragma unroll
        for (int i = 0; i < 4; ++i)
#pragma unroll
            for (int j = 0; j < 4; ++j) acc[i][j] = 0.f;

        for (int k0 = 0; k0 < HID; k0 += 16) {
            const int klen = (HID - k0 < 16) ? (HID - k0) : 16;
            __syncthreads();
            {
                int k = tid >> 4, c = tid & 15;
                if (k < klen) {
                    const float* wrow = W2 + (size_t)(k0 + k) * HID;
#pragma unroll
                    for (int i = 0; i < 4; ++i) {
                        int col = n0 + 4 * c + i;
                        sB[k][4 * c + i] = (col < HID) ? wrow[col] : 0.f;
                    }
                }
            }
            __syncthreads();
            for (int k = 0; k < klen; ++k) {
                float4 af = ld4(&sH[k0 + k][4 * tm]);
                float4 bf = ld4(&sB[k][4 * tn]);
                float a[4] = {af.x, af.y, af.z, af.w};
                float b[4] = {bf.x, bf.y, bf.z, bf.w};
#pragma unroll
                for (int i = 0; i < 4; ++i)
#pragma unroll
                    for (int j = 0; j < 4; ++j)
                        acc[i][j] = fmaf(a[i], b[j], acc[i][j]);
            }
        }
        // fold this column chunk into the final dot with W3
#pragma unroll
        for (int j = 0; j < 4; ++j) {
            int col = n0 + 4 * tn + j;
            float w3 = (col < HID) ? W3[col] : 0.f;
            float bb = (col < HID) ? b2[col] : 0.f;
#pragma unroll
            for (int i = 0; i < 4; ++i) {
                float h2 = fmaxf(acc[i][j] + bb, 0.f);
                sc[i] = fmaf(h2, w3, sc[i]);
            }
        }
    }
#pragma unroll
    for (int off = 8; off >= 1; off >>= 1) {
#pragma unroll
        for (int i = 0; i < 4; ++i) sc[i] += __shfl_down(sc[i], off, 16);
    }
    if (tn == 0) {
        float bb3 = b3[0];
#pragma unroll
        for (int i = 0; i < 4; ++i) out[row0 + 4 * tm + i] = sc[i] + bb3;
    }
}

// ---------------------------------------------------------------------------
// Attn MLP tail: P0 -> relu(+ba1) -> layers 2,3 -> attns[4096]
// ---------------------------------------------------------------------------
__global__ __launch_bounds__(256) void attn_tail_kernel(
    const float* __restrict__ P0, const float* __restrict__ ba1,
    const float* __restrict__ Wa2, const float* __restrict__ ba2,
    const float* __restrict__ Wa3, const float* __restrict__ ba3,
    float* __restrict__ attns)
{
    __shared__ float sH[PCOL][HSTR];
    __shared__ float sB[16][HSTR];
    __shared__ float sb1[PCOL];

    const int tid = threadIdx.x;
    const int t0 = blockIdx.x * 64;
    if (tid < PCOL) sb1[tid] = (tid < HID) ? ba1[tid] : 0.f;
    __syncthreads();

    for (int idx = tid; idx < 64 * (PCOL / 4); idx += 256) {
        int r = idx / (PCOL / 4), c4 = idx % (PCOL / 4);
        float4 v = ld4(&P0[(size_t)(t0 + r) * PCOL + 4 * c4]);
        float vv[4] = {v.x, v.y, v.z, v.w};
#pragma unroll
        for (int i = 0; i < 4; ++i)
            sH[4 * c4 + i][r] = fmaxf(vv[i] + sb1[4 * c4 + i], 0.f);
    }
    __syncthreads();
    mlp_tail_150(sH, sB, Wa2, ba2, Wa3, ba3, attns, t0);
}

// ---------------------------------------------------------------------------
// Span kernel: 64 spans/block. softmax over attns, gather-combine token
// projections into h1 (transposed LDS), then shared MLP tail -> scores.
// ---------------------------------------------------------------------------
__global__ __launch_bounds__(256) void span_kernel(
    const float* __restrict__ P, const float* __restrict__ attns,
    const float* __restrict__ WE1,
    const int* __restrict__ span_starts, const int* __restrict__ span_widths,
    const float* __restrict__ bs1, const float* __restrict__ Ws2,
    const float* __restrict__ bs2, const float* __restrict__ Ws3,
    const float* __restrict__ bs3, float* __restrict__ out)
{
    __shared__ float sH[PCOL][HSTR];     // 41,344 B
    __shared__ float sB[16][HSTR];       //  4,352 B
    __shared__ float s_wgt[64][W_MAX];   //  2,560 B
    __shared__ short s_pos[64][W_MAX];   //  1,280 B
    __shared__ short s_start[64], s_end[64], s_wd[64], s_bin[64];
    __shared__ float sb1[PCOL];

    const int tid = threadIdx.x;
    const int n0s = blockIdx.x * 64;

    if (tid < PCOL) sb1[tid] = (tid < HID) ? bs1[tid] : 0.f;
    if (tid < 64) {
        int st = span_starts[n0s + tid];
        int wd = span_widths[n0s + tid];
        s_start[tid] = (short)st;
        s_end[tid] = (short)(st + wd - 1);
        s_wd[tid] = (short)wd;
        s_bin[tid] = (short)((wd >= 1) + (wd >= 2) + (wd >= 3) + (wd >= 4) +
                             (wd >= 8) + (wd >= 16) + (wd >= 32) + (wd >= 64));
        float lg[W_MAX];
        float m = -1e30f;
#pragma unroll
        for (int w = 0; w < W_MAX; ++w) {
            if (w < wd) { float a = attns[st + w]; lg[w] = a; m = fmaxf(m, a); }
        }
        float sum = 0.f;
#pragma unroll
        for (int w = 0; w < W_MAX; ++w) {
            float e = (w < wd) ? __expf(lg[w] - m) : 0.f;
            lg[w] = e; sum += e;
        }
        float inv = 1.f / sum;
#pragma unroll
        for (int w = 0; w < W_MAX; ++w) {
            s_wgt[tid][w] = lg[w] * inv;
            s_pos[tid][w] = (short)(st + w);
        }
    }
    __syncthreads();

    // gather-combine: h1_pre = Ua[start] + Ub[end] + sum_w wgt*V[pos] + WE1[bin] + bs1
    {
        const float* P1 = P + (size_t)1 * T_TOK * PCOL;
        const float* P2 = P + (size_t)2 * T_TOK * PCOL;
        const float* P3 = P + (size_t)3 * T_TOK * PCOL;
        const int s = tid & 63;
        const int jg = tid >> 6;  // 0..3
        const int rs = (int)s_start[s] * PCOL;
        const int re = (int)s_end[s] * PCOL;
        const int rb = (int)s_bin[s] * PCOL;
        const int wd = s_wd[s];
        for (int c4 = jg; c4 < PCOL / 4; c4 += 4) {
            const int j = 4 * c4;
            float4 a = ld4(P1 + rs + j);
            float4 b = ld4(P2 + re + j);
            float4 c = ld4(WE1 + rb + j);
            float acc[4];
            acc[0] = a.x + b.x + c.x + sb1[j + 0];
            acc[1] = a.y + b.y + c.y + sb1[j + 1];
            acc[2] = a.z + b.z + c.z + sb1[j + 2];
            acc[3] = a.w + b.w + c.w + sb1[j + 3];
#pragma unroll
            for (int w = 0; w < W_MAX; ++w) {
                if (w < wd) {
                    float wt = s_wgt[s][w];
                    float4 v = ld4(P3 + (int)s_pos[s][w] * PCOL + j);
                    acc[0] = fmaf(wt, v.x, acc[0]);
                    acc[1] = fmaf(wt, v.y, acc[1]);
                    acc[2] = fmaf(wt, v.z, acc[2]);
                    acc[3] = fmaf(wt, v.w, acc[3]);
                }
            }
#pragma unroll
            for (int i = 0; i < 4; ++i) sH[j + i][s] = fmaxf(acc[i], 0.f);
        }
    }
    __syncthreads();
    mlp_tail_150(sH, sB, Ws2, bs2, Ws3, bs3, out, n0s);
}

// ---------------------------------------------------------------------------
extern "C" void kernel_launch(void* const* d_in, const int* in_sizes, int n_in,
                              void* d_out, int out_size, void* d_ws, size_t ws_size,
                              hipStream_t stream)
{
    const float* states      = (const float*)d_in[0];
    const float* embeds      = (const float*)d_in[1];
    const int*   span_starts = (const int*)d_in[2];
    const int*   span_widths = (const int*)d_in[3];
    const float* Wa1 = (const float*)d_in[4];
    const float* ba1 = (const float*)d_in[5];
    const float* Wa2 = (const float*)d_in[6];
    const float* ba2 = (const float*)d_in[7];
    const float* Wa3 = (const float*)d_in[8];
    const float* ba3 = (const float*)d_in[9];
    const float* width_emb = (const float*)d_in[10];
    const float* Ws1 = (const float*)d_in[11];
    const float* bs1 = (const float*)d_in[12];
    const float* Ws2 = (const float*)d_in[13];
    const float* bs2 = (const float*)d_in[14];
    const float* Ws3 = (const float*)d_in[15];
    const float* bs3 = (const float*)d_in[16];
    float* out = (float*)d_out;

    float* ws    = (float*)d_ws;
    float* attns = ws + WS_ATTNS;            // 4096
    float* WE1   = ws + WS_WE1;              // 9*152
    float* P     = ws + WS_P;                // 4*4096*152  (~10 MB total)

    hipLaunchKernelGGL(token_gemm_kernel, dim3(T_TOK / 64, 3, 4), dim3(256), 0, stream,
                       states, embeds, Wa1, Ws1, P);
    hipLaunchKernelGGL(we1_kernel, dim3(6), dim3(256), 0, stream,
                       width_emb, Ws1, WE1);
    hipLaunchKernelGGL(attn_tail_kernel, dim3(T_TOK / 64), dim3(256), 0, stream,
                       P, ba1, Wa2, ba2, Wa3, ba3, attns);
    hipLaunchKernelGGL(span_kernel, dim3(N_SPAN / 64), dim3(256), 0, stream,
                       P, attns, WE1, span_starts, span_widths,
                       bs1, Ws2, bs2, Ws3, bs3, out);
}

// Round 3
// 216.655 us; speedup vs baseline: 5.4720x; 1.3146x over previous
//
#include <hip/hip_runtime.h>
#include <math.h>

#define T_TOK 4096
#define A_DIM 1024
#define E_DIM 512
#define N_SPAN 32768
#define W_MAX 10
#define HID 150
#define FD 20

#define PCOL 152            // P row stride (floats)
#define KP2 160             // padded K/N for the 150x150 layers

// ---- workspace layout (float offsets) ----
#define WS_ATTNS 0
#define WS_WE1   4096
#define WS_P     6144
#define WS_WPACK (6144 + 4 * 4096 * 152)     // = 2,496,512 floats (16B aligned)
// within wpack (ushort offsets):
#define WP_A1  0
#define WP_S1A 163840
#define WP_S1B 327680
#define WP_V   491520
#define WP_A2  573440
#define WP_S2  599040
#define WP_TOTAL 624640

typedef short  bf16x8 __attribute__((ext_vector_type(8)));
typedef float  f32x4  __attribute__((ext_vector_type(4)));

__device__ __forceinline__ float4 ld4(const float* p) { return *(const float4*)p; }

__device__ __forceinline__ unsigned short f2bf(float f) {
    unsigned u = __float_as_uint(f);
    unsigned r = u + 0x7fffu + ((u >> 16) & 1u);   // RNE
    return (unsigned short)(r >> 16);
}

__device__ __forceinline__ bf16x8 zero_frag() {
    bf16x8 f;
#pragma unroll
    for (int j = 0; j < 8; ++j) f[j] = 0;
    return f;
}

// build an A-frag (8 consecutive k) from fp32 memory
__device__ __forceinline__ bf16x8 cvt_frag(const float* p) {
    float4 u = ld4(p), v = ld4(p + 4);
    bf16x8 f;
    f[0] = (short)f2bf(u.x); f[1] = (short)f2bf(u.y);
    f[2] = (short)f2bf(u.z); f[3] = (short)f2bf(u.w);
    f[4] = (short)f2bf(v.x); f[5] = (short)f2bf(v.y);
    f[6] = (short)f2bf(v.z); f[7] = (short)f2bf(v.w);
    return f;
}

// ---------------------------------------------------------------------------
// Prepack: weights -> bf16, n-major [n][k] (B-operand layout), K padded
// ---------------------------------------------------------------------------
__global__ __launch_bounds__(256) void prepack_kernel(
    const float* __restrict__ Wa1, const float* __restrict__ Ws1,
    const float* __restrict__ Wa2, const float* __restrict__ Ws2,
    unsigned short* __restrict__ wp)
{
    int idx = blockIdx.x * 256 + threadIdx.x;
    if (idx >= WP_TOTAL) return;
    float v = 0.f;
    if (idx < WP_V) {                       // three 160x1024 state blocks
        int which = idx / 163840, r = idx % 163840;
        int n = r >> 10, k = r & 1023;
        if (n < HID) {
            if (which == 0)      v = Wa1[(size_t)k * HID + n];
            else if (which == 1) v = Ws1[(size_t)k * HID + n];
            else                 v = Ws1[(size_t)(1024 + k) * HID + n];
        }
    } else if (idx < WP_A2) {               // V: 160x512 (embeds block)
        int r = idx - WP_V;
        int n = r >> 9, k = r & 511;
        if (n < HID) v = Ws1[(size_t)(2048 + k) * HID + n];
    } else if (idx < WP_S2) {               // Wa2: 160x160
        int r = idx - WP_A2;
        int n = r / KP2, k = r % KP2;
        if (n < HID && k < HID) v = Wa2[(size_t)k * HID + n];
    } else {                                // Ws2: 160x160
        int r = idx - WP_S2;
        int n = r / KP2, k = r % KP2;
        if (n < HID && k < HID) v = Ws2[(size_t)k * HID + n];
    }
    wp[idx] = f2bf(v);
}

// ---------------------------------------------------------------------------
// Token projections via MFMA: P[g][4096][152] = X_g @ W_g (no bias).
// One wave per block: 32 rows x 160 cols of group g. No LDS, no barriers:
// A-frags built in-register from fp32, B-frags direct b128 from packed bf16.
// ---------------------------------------------------------------------------
__global__ __launch_bounds__(64) void token_gemm_kernel(
    const float* __restrict__ states, const float* __restrict__ embeds,
    const unsigned short* __restrict__ wp, float* __restrict__ P)
{
    const int g = blockIdx.y;
    const int m0 = blockIdx.x * 32;
    const int lane = threadIdx.x, l15 = lane & 15, quad = lane >> 4;

    const float* X = (g == 3) ? embeds : states;
    const int K = (g == 3) ? 512 : 1024;     // == X row stride
    const unsigned short* B = wp + ((g == 0) ? WP_A1 : (g == 1) ? WP_S1A
                                    : (g == 2) ? WP_S1B : WP_V);

    f32x4 acc[2][10];
#pragma unroll
    for (int mt = 0; mt < 2; ++mt)
#pragma unroll
        for (int nt = 0; nt < 10; ++nt)
#pragma unroll
            for (int i = 0; i < 4; ++i) acc[mt][nt][i] = 0.f;

    const float* a0 = X + (size_t)(m0 + l15) * K + quad * 8;
    const float* a1 = a0 + (size_t)16 * K;
    const unsigned short* bb = B + (size_t)l15 * K + quad * 8;

#pragma unroll 2
    for (int k0 = 0; k0 < K; k0 += 32) {
        bf16x8 af0 = cvt_frag(a0 + k0);
        bf16x8 af1 = cvt_frag(a1 + k0);
#pragma unroll
        for (int nt = 0; nt < 10; ++nt) {
            bf16x8 bf = *(const bf16x8*)(bb + (size_t)nt * 16 * K + k0);
            acc[0][nt] = __builtin_amdgcn_mfma_f32_16x16x32_bf16(af0, bf, acc[0][nt], 0, 0, 0);
            acc[1][nt] = __builtin_amdgcn_mfma_f32_16x16x32_bf16(af1, bf, acc[1][nt], 0, 0, 0);
        }
    }

    float* Pg = P + (size_t)g * T_TOK * PCOL;
#pragma unroll
    for (int nt = 0; nt < 10; ++nt) {
        int col = nt * 16 + l15;
        if (col < PCOL) {
#pragma unroll
            for (int mt = 0; mt < 2; ++mt)
#pragma unroll
                for (int i = 0; i < 4; ++i)
                    Pg[(size_t)(m0 + mt * 16 + quad * 4 + i) * PCOL + col] = acc[mt][nt][i];
        }
    }
}

// ---------------------------------------------------------------------------
// WE1[9][152] = width_emb @ Ws1[2560:2580]  (tiny, fp32)
// ---------------------------------------------------------------------------
__global__ void we1_kernel(const float* __restrict__ width_emb,
                           const float* __restrict__ Ws1,
                           float* __restrict__ WE1)
{
    int idx = blockIdx.x * 256 + threadIdx.x;
    if (idx >= 9 * PCOL) return;
    int b = idx / PCOL, j = idx % PCOL;
    float acc = 0.f;
    if (j < HID) {
        for (int k = 0; k < FD; ++k)
            acc = fmaf(width_emb[b * FD + k], Ws1[(size_t)(2560 + k) * HID + j], acc);
    }
    WE1[idx] = acc;
}

// ---------------------------------------------------------------------------
// Attn tail: one wave per 16 tokens. h1 = relu(P0 + ba1) built in-register as
// A-frags; layer2 MFMA vs packed Wa2; layer3 via shuffle reduce. No LDS.
// ---------------------------------------------------------------------------
__global__ __launch_bounds__(64) void attn_tail_kernel(
    const float* __restrict__ P0, const float* __restrict__ ba1,
    const unsigned short* __restrict__ wp, const float* __restrict__ ba2,
    const float* __restrict__ Wa3, const float* __restrict__ ba3,
    float* __restrict__ attns)
{
    const int t0 = blockIdx.x * 16;
    const int lane = threadIdx.x, l15 = lane & 15, quad = lane >> 4;

    f32x4 acc[10];
#pragma unroll
    for (int nt = 0; nt < 10; ++nt)
#pragma unroll
        for (int i = 0; i < 4; ++i) acc[nt][i] = 0.f;

    const float* prow = P0 + (size_t)(t0 + l15) * PCOL;
    const unsigned short* bb = wp + WP_A2 + l15 * KP2 + quad * 8;

#pragma unroll
    for (int c = 0; c < 5; ++c) {
        const int k0 = c * 32;
        const int kk = k0 + quad * 8;
        bf16x8 af;
        if (kk < PCOL) {
            float4 u = ld4(prow + kk), v = ld4(prow + kk + 4);
            float x[8] = {u.x, u.y, u.z, u.w, v.x, v.y, v.z, v.w};
#pragma unroll
            for (int j = 0; j < 8; ++j) {
                float b = (kk + j < HID) ? ba1[kk + j] : 0.f;
                af[j] = (short)f2bf(fmaxf(x[j] + b, 0.f));
            }
        } else {
            af = zero_frag();
        }
#pragma unroll
        for (int nt = 0; nt < 10; ++nt) {
            bf16x8 bf = *(const bf16x8*)(bb + nt * 16 * KP2 + k0);
            acc[nt] = __builtin_amdgcn_mfma_f32_16x16x32_bf16(af, bf, acc[nt], 0, 0, 0);
        }
    }

    float sc[4] = {0.f, 0.f, 0.f, 0.f};
#pragma unroll
    for (int nt = 0; nt < 10; ++nt) {
        int col = nt * 16 + l15;
        float w3 = (col < HID) ? Wa3[col] : 0.f;
        float b2 = (col < HID) ? ba2[col] : 0.f;
#pragma unroll
        for (int i = 0; i < 4; ++i)
            sc[i] = fmaf(fmaxf(acc[nt][i] + b2, 0.f), w3, sc[i]);
    }
#pragma unroll
    for (int off = 8; off >= 1; off >>= 1)
#pragma unroll
        for (int i = 0; i < 4; ++i) sc[i] += __shfl_down(sc[i], off, 16);
    if (l15 == 0) {
        float b3 = ba3[0];
#pragma unroll
        for (int i = 0; i < 4; ++i) attns[t0 + quad * 4 + i] = sc[i] + b3;
    }
}

// ---------------------------------------------------------------------------
// Span kernel: 64 spans/block. Softmax + fp32 gather-combine of token
// projections -> h1 bf16 in LDS [span][k]; layer2 MFMA (B direct from
// global packed Ws2); layer3 shuffle-reduce + LDS partials. One main barrier.
// ---------------------------------------------------------------------------
__global__ __launch_bounds__(256) void span_kernel(
    const float* __restrict__ P, const float* __restrict__ attns,
    const float* __restrict__ WE1, const unsigned short* __restrict__ wp,
    const int* __restrict__ span_starts, const int* __restrict__ span_widths,
    const float* __restrict__ bs1, const float* __restrict__ bs2,
    const float* __restrict__ Ws3, const float* __restrict__ bs3,
    float* __restrict__ out)
{
    __shared__ unsigned short sHb[64][168];   // h1 bf16, stride 168 (21x8)
    __shared__ float s_wgt[64][W_MAX];
    __shared__ short s_pos[64][W_MAX];
    __shared__ short s_start[64], s_end[64], s_bin[64], s_wd[64];
    __shared__ float sPart[4][64];
    __shared__ float sb1[PCOL];

    const int tid = threadIdx.x;
    const int n0s = blockIdx.x * 64;

    if (tid < PCOL) sb1[tid] = (tid < HID) ? bs1[tid] : 0.f;
    if (tid < 64) {
        int st = span_starts[n0s + tid];
        int wd = span_widths[n0s + tid];
        s_start[tid] = (short)st;
        s_end[tid] = (short)(st + wd - 1);
        s_wd[tid] = (short)wd;
        s_bin[tid] = (short)((wd >= 1) + (wd >= 2) + (wd >= 3) + (wd >= 4) +
                             (wd >= 8) + (wd >= 16) + (wd >= 32) + (wd >= 64));
        float lg[W_MAX];
        float m = -1e30f;
#pragma unroll
        for (int w = 0; w < W_MAX; ++w)
            if (w < wd) { float a = attns[st + w]; lg[w] = a; m = fmaxf(m, a); }
        float sum = 0.f;
#pragma unroll
        for (int w = 0; w < W_MAX; ++w) {
            float e = (w < wd) ? __expf(lg[w] - m) : 0.f;
            lg[w] = e; sum += e;
        }
        float inv = 1.f / sum;
#pragma unroll
        for (int w = 0; w < W_MAX; ++w) {
            s_wgt[tid][w] = lg[w] * inv;
            s_pos[tid][w] = (short)(st + w);
        }
        // zero the k-pad (cols 152..159)
        ushort4 z = {0, 0, 0, 0};
        *(ushort4*)&sHb[tid][152] = z;
        *(ushort4*)&sHb[tid][156] = z;
    }
    __syncthreads();

    // gather-combine (fp32) -> relu -> bf16 into sHb[span][k]
    {
        const float* P1 = P + (size_t)1 * T_TOK * PCOL;
        const float* P2 = P + (size_t)2 * T_TOK * PCOL;
        const float* P3 = P + (size_t)3 * T_TOK * PCOL;
        const int s = tid & 63;
        const int jg = tid >> 6;
        const int rs = (int)s_start[s] * PCOL;
        const int re = (int)s_end[s] * PCOL;
        const int rb = (int)s_bin[s] * PCOL;
        const int wd = s_wd[s];
        for (int c4 = jg; c4 < PCOL / 4; c4 += 4) {
            const int j = 4 * c4;
            float4 a = ld4(P1 + rs + j);
            float4 b = ld4(P2 + re + j);
            float4 c = ld4(WE1 + rb + j);
            float acc[4];
            acc[0] = a.x + b.x + c.x + sb1[j + 0];
            acc[1] = a.y + b.y + c.y + sb1[j + 1];
            acc[2] = a.z + b.z + c.z + sb1[j + 2];
            acc[3] = a.w + b.w + c.w + sb1[j + 3];
#pragma unroll
            for (int w = 0; w < W_MAX; ++w) {
                if (w < wd) {
                    float wt = s_wgt[s][w];
                    const float* ep = P3 + (int)s_pos[s][w] * PCOL + j;
                    float4 v = ld4(ep);
                    acc[0] = fmaf(wt, v.x, acc[0]);
                    acc[1] = fmaf(wt, v.y, acc[1]);
                    acc[2] = fmaf(wt, v.z, acc[2]);
                    acc[3] = fmaf(wt, v.w, acc[3]);
                }
            }
            ushort4 pk;
            pk.x = f2bf(fmaxf(acc[0], 0.f));
            pk.y = f2bf(fmaxf(acc[1], 0.f));
            pk.z = f2bf(fmaxf(acc[2], 0.f));
            pk.w = f2bf(fmaxf(acc[3], 0.f));
            *(ushort4*)&sHb[s][j] = pk;
        }
    }
    __syncthreads();

    // layer2 MFMA: M=64 (4 m-tiles), N=160 (10 n-tiles split over 4 waves)
    const int wv = tid >> 6;
    const int lane = tid & 63, l15 = lane & 15, quad = lane >> 4;
    const int ntb = (wv < 2) ? 3 * wv : 6 + 2 * (wv - 2);
    const int cnt = (wv < 2) ? 3 : 2;

    f32x4 acc2[4][3];
#pragma unroll
    for (int mt = 0; mt < 4; ++mt)
#pragma unroll
        for (int t = 0; t < 3; ++t)
#pragma unroll
            for (int i = 0; i < 4; ++i) acc2[mt][t][i] = 0.f;

    const unsigned short* bb = wp + WP_S2 + l15 * KP2 + quad * 8;

#pragma unroll
    for (int c = 0; c < 5; ++c) {
        const int k0 = c * 32;
        bf16x8 afr[4];
#pragma unroll
        for (int mt = 0; mt < 4; ++mt)
            afr[mt] = *(const bf16x8*)&sHb[mt * 16 + l15][k0 + quad * 8];
        for (int t = 0; t < cnt; ++t) {
            bf16x8 bfr = *(const bf16x8*)(bb + (ntb + t) * 16 * KP2 + k0);
#pragma unroll
            for (int mt = 0; mt < 4; ++mt)
                acc2[mt][t] = __builtin_amdgcn_mfma_f32_16x16x32_bf16(afr[mt], bfr, acc2[mt][t], 0, 0, 0);
        }
    }

    // layer3: relu(acc2 + bs2) . Ws3, partial per wave
    float sc[4][4];
#pragma unroll
    for (int mt = 0; mt < 4; ++mt)
#pragma unroll
        for (int i = 0; i < 4; ++i) sc[mt][i] = 0.f;

    for (int t = 0; t < cnt; ++t) {
        int col = (ntb + t) * 16 + l15;
        float w3 = (col < HID) ? Ws3[col] : 0.f;
        float b2 = (col < HID) ? bs2[col] : 0.f;
#pragma unroll
        for (int mt = 0; mt < 4; ++mt)
#pragma unroll
            for (int i = 0; i < 4; ++i)
                sc[mt][i] = fmaf(fmaxf(acc2[mt][t][i] + b2, 0.f), w3, sc[mt][i]);
    }
#pragma unroll
    for (int off = 8; off >= 1; off >>= 1)
#pragma unroll
        for (int mt = 0; mt < 4; ++mt)
#pragma unroll
            for (int i = 0; i < 4; ++i)
                sc[mt][i] += __shfl_down(sc[mt][i], off, 16);
    if (l15 == 0) {
#pragma unroll
        for (int mt = 0; mt < 4; ++mt)
#pragma unroll
            for (int i = 0; i < 4; ++i)
                sPart[wv][mt * 16 + quad * 4 + i] = sc[mt][i];
    }
    __syncthreads();
    if (tid < 64)
        out[n0s + tid] = sPart[0][tid] + sPart[1][tid] + sPart[2][tid] + sPart[3][tid] + bs3[0];
}

// ---------------------------------------------------------------------------
extern "C" void kernel_launch(void* const* d_in, const int* in_sizes, int n_in,
                              void* d_out, int out_size, void* d_ws, size_t ws_size,
                              hipStream_t stream)
{
    const float* states      = (const float*)d_in[0];
    const float* embeds      = (const float*)d_in[1];
    const int*   span_starts = (const int*)d_in[2];
    const int*   span_widths = (const int*)d_in[3];
    const float* Wa1 = (const float*)d_in[4];
    const float* ba1 = (const float*)d_in[5];
    const float* Wa2 = (const float*)d_in[6];
    const float* ba2 = (const float*)d_in[7];
    const float* Wa3 = (const float*)d_in[8];
    const float* ba3 = (const float*)d_in[9];
    const float* width_emb = (const float*)d_in[10];
    const float* Ws1 = (const float*)d_in[11];
    const float* bs1 = (const float*)d_in[12];
    const float* Ws2 = (const float*)d_in[13];
    const float* bs2 = (const float*)d_in[14];
    const float* Ws3 = (const float*)d_in[15];
    const float* bs3 = (const float*)d_in[16];
    float* out = (float*)d_out;

    float* ws    = (float*)d_ws;
    float* attns = ws + WS_ATTNS;
    float* WE1   = ws + WS_WE1;
    float* P     = ws + WS_P;
    unsigned short* wpack = (unsigned short*)(ws + WS_WPACK);

    hipLaunchKernelGGL(prepack_kernel, dim3((WP_TOTAL + 255) / 256), dim3(256), 0, stream,
                       Wa1, Ws1, Wa2, Ws2, wpack);
    hipLaunchKernelGGL(token_gemm_kernel, dim3(T_TOK / 32, 4), dim3(64), 0, stream,
                       states, embeds, wpack, P);
    hipLaunchKernelGGL(we1_kernel, dim3(6), dim3(256), 0, stream,
                       width_emb, Ws1, WE1);
    hipLaunchKernelGGL(attn_tail_kernel, dim3(T_TOK / 16), dim3(64), 0, stream,
                       P, ba1, wpack, ba2, Wa3, ba3, attns);
    hipLaunchKernelGGL(span_kernel, dim3(N_SPAN / 64), dim3(256), 0, stream,
                       P, attns, WE1, wpack, span_starts, span_widths,
                       bs1, bs2, Ws3, bs3, out);
}